// Round 2
// baseline (605.130 us; speedup 1.0000x reference)
//
#include <hip/hip_runtime.h>
#include <hip/hip_bf16.h>
#include <stdint.h>

#define B_ 32
#define S_ 2048
#define H_ 1024

typedef __attribute__((ext_vector_type(8))) short short8;
typedef __attribute__((ext_vector_type(4))) float floatx4;

__device__ inline unsigned short f32_bf16(float f) {
    union { float f; unsigned u; } v; v.f = f;
    unsigned u = v.u;
    u += 0x7fff + ((u >> 16) & 1);   // round-to-nearest-even
    return (unsigned short)(u >> 16);
}
__device__ inline unsigned pack_bf2(float a, float b) {
    return (unsigned)f32_bf16(a) | ((unsigned)f32_bf16(b) << 16);
}
__device__ inline float bf_lo(unsigned u) { union { unsigned u; float f; } v; v.u = u << 16; return v.f; }
__device__ inline float bf_hi(unsigned u) { union { unsigned u; float f; } v; v.u = u & 0xffff0000u; return v.f; }

__device__ inline float tanh_fast(float x) {
    float e = __expf(2.0f * x);
    return 1.0f - 2.0f / (e + 1.0f);
}

__device__ inline void gld16(const void* g, void* l) {
    __builtin_amdgcn_global_load_lds(
        (const __attribute__((address_space(1))) unsigned int*)g,
        (__attribute__((address_space(3))) unsigned int*)l, 16, 0, 0);
}

// ---------------- prep: keys->bf16, Ua->bf16, qproj --------------------------
#define KCVT_BLOCKS 32768          // 64M elems / 2048 per block
#define UACVT_BLOCKS 512           // 1M elems / 2048 per block
#define QP_BLOCKS 64
__global__ void k_prep(const float* __restrict__ keys, unsigned short* __restrict__ keysbf,
                       const float* __restrict__ ua, unsigned short* __restrict__ uab,
                       const float* __restrict__ query, const float* __restrict__ Wa_w,
                       const float* __restrict__ Wa_b, const float* __restrict__ Ua_b,
                       float* __restrict__ qsum) {
    int blk = blockIdx.x, t = threadIdx.x;
    if (blk < KCVT_BLOCKS + UACVT_BLOCKS) {
        const float* src; unsigned short* dst; size_t base;
        if (blk < KCVT_BLOCKS) { src = keys; dst = keysbf; base = (size_t)blk * 2048; }
        else { src = ua; dst = uab; base = (size_t)(blk - KCVT_BLOCKS) * 2048; }
        float4 v0 = *(const float4*)(src + base + t * 4);
        float4 v1 = *(const float4*)(src + base + 1024 + t * 4);
        *(uint2*)(dst + base + t * 4)        = make_uint2(pack_bf2(v0.x, v0.y), pack_bf2(v0.z, v0.w));
        *(uint2*)(dst + base + 1024 + t * 4) = make_uint2(pack_bf2(v1.x, v1.y), pack_bf2(v1.z, v1.w));
    } else {
        // qproj: qsum[b,g] = query[b]·Wa_w[g] + Wa_b[g] + Ua_b[g]
        __shared__ float qs_l[32][68];
        int g0 = (blk - KCVT_BLOCKS - UACVT_BLOCKS) * 16;
        int r = t >> 4, l = t & 15;
        int g = g0 + r;
        float acc[32];
#pragma unroll
        for (int b = 0; b < 32; ++b) acc[b] = 0.0f;
        int sb = t >> 3, sc = (t & 7) * 8;
        for (int hc = 0; hc < 16; ++hc) {
            __syncthreads();
            float4 v0 = *(const float4*)(query + (size_t)sb * H_ + hc * 64 + sc);
            float4 v1 = *(const float4*)(query + (size_t)sb * H_ + hc * 64 + sc + 4);
            *(float4*)&qs_l[sb][sc]     = v0;
            *(float4*)&qs_l[sb][sc + 4] = v1;
            __syncthreads();
            float4 w = *(const float4*)(Wa_w + (size_t)g * H_ + hc * 64 + l * 4);
#pragma unroll
            for (int b = 0; b < 32; ++b) {
                float4 q4 = *(const float4*)&qs_l[b][l * 4];
                acc[b] += w.x * q4.x + w.y * q4.y + w.z * q4.z + w.w * q4.w;
            }
        }
#pragma unroll
        for (int b = 0; b < 32; ++b) {
            float a = acc[b];
            a += __shfl_xor(a, 1); a += __shfl_xor(a, 2);
            a += __shfl_xor(a, 4); a += __shfl_xor(a, 8);
            acc[b] = a;
        }
        if (l == 0) {
            float bias = Wa_b[g] + Ua_b[g];
#pragma unroll
            for (int b = 0; b < 32; ++b) qsum[b * H_ + g] = acc[b] + bias;
        }
    }
}

// ---------------- fused GEMM + tanh + Va reduction ---------------------------
// 256x256 tile, BK=64, 8 waves (2M x 4N), 8-phase schedule, reads-BEFORE-barrier
// (m201 "derived waits" port): each phase = [ds_read; stage] -> barrier ->
// MFMA -> vmcnt -> barrier. LDS service overlaps barrier wait + prior phase's
// matrix-pipe drain (independent C-quadrants across phases).
// Half-tiles of step t: A0,B0,B1,A1 staged in that order during step t-1.
// Reads: p1: A0,B0; p2: B1; p3: A1; p4: none.
// Steady-state queue at step top: [B1(t),A1(t)] = 4 outstanding.
//   p1 stages A0(t+1), vmcnt(4) drains B1(t)   (read at p2 top)
//   p2 stages B0(t+1), vmcnt(4) drains A1(t)   (read at p3 top)
//   p3 stages B1(t+1), no vmcnt                (p4 reads nothing)
//   p4 stages A1(t+1), vmcnt(4) drains A0,B0(t+1) (read at p1 top of t+1)
// Lead time >= 2 phases for every drain; publication = vmcnt -> barrier -> read.
#define BM 256
#define BN 256
#define BK 64

#define VMCNT(S) asm volatile("s_waitcnt vmcnt(" S ")" ::: "memory")

#define STAGE_A(SB, h, KO) do {                                                       \
    gld16(pAj[0] + (h) * 64 * H_ + (KO), &Al[(SB) * 16384 + (h) * 8192 + sA]);        \
    gld16(pAj[1] + (h) * 64 * H_ + (KO), &Al[(SB) * 16384 + (h) * 8192 + sA + 512]);  \
} while (0)
#define STAGE_B(SB, h, KO) do {                                                       \
    gld16(pBj[0] + (h) * 32 * H_ + (KO), &Bl[(SB) * 16384 + (h) * 8192 + sA]);        \
    gld16(pBj[1] + (h) * 32 * H_ + (KO), &Bl[(SB) * 16384 + (h) * 8192 + sA + 512]);  \
} while (0)

#define MFMA_BF16 __builtin_amdgcn_mfma_f32_16x16x32_bf16

// One K-step (BK=64): 4 phases. RB = read-buffer elem offset (0/16384),
// SB = stage-buffer index (0/1), KO = k elem offset staged (next step),
// W1/W2 = vmcnt immediates (strings), DOST = stage (0 on last),
// DOV4 = emit phase-4 vmcnt (0 on last).
#define STEP(RB, SB, KO, W1, W2, DOST, DOV4) do {                                      \
    /* phase 1: read A0,B0(cur); stage A0(next); MFMA Q00; vmcnt; barrier */           \
    _Pragma("unroll") for (int ii_ = 0; ii_ < 4; ++ii_) {                              \
        af[ii_][0] = *(const short8*)&Al[(RB) + arA + ii_ * 1024 + cs0];               \
        af[ii_][1] = *(const short8*)&Al[(RB) + arA + ii_ * 1024 + cs1]; }             \
    _Pragma("unroll") for (int jj_ = 0; jj_ < 2; ++jj_) {                              \
        bfa[jj_][0] = *(const short8*)&Bl[(RB) + brB + jj_ * 1024 + cs0];              \
        bfa[jj_][1] = *(const short8*)&Bl[(RB) + brB + jj_ * 1024 + cs1]; }            \
    if (DOST) STAGE_A(SB, 0, KO);                                                      \
    __builtin_amdgcn_s_barrier();                                                      \
    __builtin_amdgcn_s_setprio(1);                                                     \
    _Pragma("unroll") for (int ii_ = 0; ii_ < 4; ++ii_)                                \
    _Pragma("unroll") for (int jj_ = 0; jj_ < 2; ++jj_) {                              \
        acc[ii_][jj_] = MFMA_BF16(af[ii_][0], bfa[jj_][0], acc[ii_][jj_], 0, 0, 0);    \
        acc[ii_][jj_] = MFMA_BF16(af[ii_][1], bfa[jj_][1], acc[ii_][jj_], 0, 0, 0); }  \
    __builtin_amdgcn_s_setprio(0);                                                     \
    VMCNT(W1);                                                                         \
    __builtin_amdgcn_s_barrier();                                                      \
    /* phase 2: read B1(cur); stage B0(next); MFMA Q01; vmcnt; barrier */              \
    _Pragma("unroll") for (int jj_ = 0; jj_ < 2; ++jj_) {                              \
        bfb[jj_][0] = *(const short8*)&Bl[(RB) + 8192 + brB + jj_ * 1024 + cs0];       \
        bfb[jj_][1] = *(const short8*)&Bl[(RB) + 8192 + brB + jj_ * 1024 + cs1]; }     \
    if (DOST) STAGE_B(SB, 0, KO);                                                      \
    __builtin_amdgcn_s_barrier();                                                      \
    __builtin_amdgcn_s_setprio(1);                                                     \
    _Pragma("unroll") for (int ii_ = 0; ii_ < 4; ++ii_)                                \
    _Pragma("unroll") for (int jj_ = 0; jj_ < 2; ++jj_) {                              \
        acc[ii_][jj_ + 2] = MFMA_BF16(af[ii_][0], bfb[jj_][0], acc[ii_][jj_ + 2], 0, 0, 0); \
        acc[ii_][jj_ + 2] = MFMA_BF16(af[ii_][1], bfb[jj_][1], acc[ii_][jj_ + 2], 0, 0, 0); } \
    __builtin_amdgcn_s_setprio(0);                                                     \
    VMCNT(W2);                                                                         \
    __builtin_amdgcn_s_barrier();                                                      \
    /* phase 3: read A1(cur); stage B1(next); MFMA Q10; barrier (no vmcnt) */          \
    _Pragma("unroll") for (int ii_ = 0; ii_ < 4; ++ii_) {                              \
        af[ii_][0] = *(const short8*)&Al[(RB) + 8192 + arA + ii_ * 1024 + cs0];        \
        af[ii_][1] = *(const short8*)&Al[(RB) + 8192 + arA + ii_ * 1024 + cs1]; }      \
    if (DOST) STAGE_B(SB, 1, KO);                                                      \
    __builtin_amdgcn_s_barrier();                                                      \
    __builtin_amdgcn_s_setprio(1);                                                     \
    _Pragma("unroll") for (int ii_ = 0; ii_ < 4; ++ii_)                                \
    _Pragma("unroll") for (int jj_ = 0; jj_ < 2; ++jj_) {                              \
        acc[ii_ + 4][jj_] = MFMA_BF16(af[ii_][0], bfa[jj_][0], acc[ii_ + 4][jj_], 0, 0, 0); \
        acc[ii_ + 4][jj_] = MFMA_BF16(af[ii_][1], bfa[jj_][1], acc[ii_ + 4][jj_], 0, 0, 0); } \
    __builtin_amdgcn_s_setprio(0);                                                     \
    __builtin_amdgcn_s_barrier();                                                      \
    /* phase 4: stage A1(next); MFMA Q11; vmcnt publishes A0,B0(next); barrier */      \
    if (DOST) STAGE_A(SB, 1, KO);                                                      \
    __builtin_amdgcn_s_barrier();                                                      \
    __builtin_amdgcn_s_setprio(1);                                                     \
    _Pragma("unroll") for (int ii_ = 0; ii_ < 4; ++ii_)                                \
    _Pragma("unroll") for (int jj_ = 0; jj_ < 2; ++jj_) {                              \
        acc[ii_ + 4][jj_ + 2] = MFMA_BF16(af[ii_][0], bfb[jj_][0], acc[ii_ + 4][jj_ + 2], 0, 0, 0); \
        acc[ii_ + 4][jj_ + 2] = MFMA_BF16(af[ii_][1], bfb[jj_][1], acc[ii_ + 4][jj_ + 2], 0, 0, 0); } \
    __builtin_amdgcn_s_setprio(0);                                                     \
    if (DOV4) VMCNT("4");                                                              \
    __builtin_amdgcn_s_barrier();                                                      \
} while (0)

__global__ __launch_bounds__(512, 2) void k_scores(
    const unsigned short* __restrict__ keysbf, const unsigned short* __restrict__ uab,
    const float* __restrict__ qsum, const float* __restrict__ va,
    float* __restrict__ scores_p)
{
    __shared__ unsigned short Al[32768];   // 64 KB: [buf2][half2][128][64] swizzled
    __shared__ unsigned short Bl[32768];   // 64 KB

    int bx = blockIdx.x;                   // 1024 blocks: 256 m-tiles x 4 nc
    int x  = bx & 7;                       // XCD
    int i  = bx >> 3;
    int tile_m = x * 32 + (i >> 2);
    int nc     = i & 3;
    int m_base = tile_m * BM;
    int b      = m_base >> 11;
    int g0     = nc * BN;

    int tid = threadIdx.x;
    int wid = tid >> 6, lane = tid & 63;
    int wm = wid >> 2, wn = wid & 3;       // 2 x 4 wave grid; wave tile 128 x 64
    int q = lane >> 4, cn = lane & 15;
    int c7 = cn & 7;

    // ---- staging geometry: chunk (wid*2+j) covers half-local rows chunk*8..+8.
    // phys col-group (lane&7) holds global col-group (lane&7)^(hlrow&7).
    int rl8 = lane >> 3;
    int gcg = (lane & 7) ^ rl8;
    int ch0 = wid * 2;
    const unsigned short* pAj[2];
    const unsigned short* pBj[2];
#pragma unroll
    for (int j = 0; j < 2; ++j) {
        int hlrow = (ch0 + j) * 8 + rl8;
        // A half-local row -> global row (half0; half1 adds 64*H_ at use)
        pAj[j] = keysbf + (size_t)(m_base + (hlrow >> 6) * 128 + (hlrow & 63)) * H_ + gcg * 8;
        // B half-local row -> global g-row (half0; half1 adds 32*H_ at use)
        pBj[j] = uab    + (size_t)(g0 + (hlrow >> 5) * 64 + (hlrow & 31)) * H_ + gcg * 8;
    }
    int sA = ch0 * 512;                    // LDS elem offset of this wave's chunk 0

    // ---- fragment read bases (within one half of one buffer)
    int arA = wm * 4096 + cn * 64;         // A: hr = wm*64 + (ii&3)*16 + cn
    int brB = wn * 2048 + cn * 64;         // B: hr = wn*32 + (jj&1)*16 + cn
    int cs0 = (q ^ c7) * 8;                // phys col-group, kk=0
    int cs1 = ((4 + q) ^ c7) * 8;          // phys col-group, kk=1

    floatx4 acc[8][4];
#pragma unroll
    for (int ii = 0; ii < 8; ++ii)
#pragma unroll
        for (int jj = 0; jj < 4; ++jj)
            acc[ii][jj] = (floatx4)(0.0f);

    short8 af[4][2], bfa[2][2], bfb[2][2];

    // ---- prologue: stage K-step 0 into buf0, queue order [A0, B0, B1, A1];
    // publish A0,B0 (vmcnt 4 -> barrier) for step 0 phase-1 reads.
    STAGE_A(0, 0, 0);
    STAGE_B(0, 0, 0);
    STAGE_B(0, 1, 0);
    STAGE_A(0, 1, 0);
    VMCNT("4");
    __builtin_amdgcn_s_barrier();

    // ---- main loop: 16 K-steps total
#pragma unroll 1
    for (int it = 0; it < 7; ++it) {
        int ko = it * 128 + 64;            // stage k-offset for step 2*it+1
        STEP(0,     1, ko,      "4", "4", 1, 1);
        STEP(16384, 0, ko + 64, "4", "4", 1, 1);
    }
    STEP(0,     1, 960, "4", "4", 1, 1);   // t=14, stages t=15 into buf1
    STEP(16384, 0, 0,   "2", "0", 0, 0);   // t=15, peeled drain 2->0

    // ---- epilogue: scores partial = sum_g Va[g] * tanh(qsum[b,g] + C)
    float qs[4], vw[4];
#pragma unroll
    for (int jj = 0; jj < 4; ++jj) {
        int g = g0 + wn * 64 + jj * 16 + cn;
        qs[jj] = qsum[b * H_ + g];
        vw[jj] = va[g];
    }
    float* slab = scores_p + (size_t)(wn * 4 + nc) * (B_ * S_) + b * S_;
#pragma unroll
    for (int ii = 0; ii < 8; ++ii) {
        float rs[4] = {0.f, 0.f, 0.f, 0.f};
#pragma unroll
        for (int jj = 0; jj < 4; ++jj) {
#pragma unroll
            for (int r = 0; r < 4; ++r)
                rs[r] += vw[jj] * tanh_fast(qs[jj] + acc[ii][jj][r]);
        }
#pragma unroll
        for (int r = 0; r < 4; ++r) {
            rs[r] += __shfl_xor(rs[r], 1); rs[r] += __shfl_xor(rs[r], 2);
            rs[r] += __shfl_xor(rs[r], 4); rs[r] += __shfl_xor(rs[r], 8);
        }
        if (cn == 0) {
            int msrow = (m_base & (S_ - 1)) + wm * 128 + ii * 16 + q * 4;
            float* sp = slab + msrow;
            sp[0] = rs[0]; sp[1] = rs[1]; sp[2] = rs[2]; sp[3] = rs[3];
        }
    }
}

// ---------------- softmax over S per batch (reduces 16 partial slabs) --------
__global__ void k_softmax(const float* __restrict__ scores_p, float* __restrict__ weights) {
    int b = blockIdx.x;
    int t = threadIdx.x;
    __shared__ float red[4];
    float v[8];
    float mx = -1e30f;
#pragma unroll
    for (int k = 0; k < 8; ++k) {
        int idx = b * S_ + t + k * 256;
        float s = 0.0f;
#pragma unroll
        for (int p = 0; p < 16; ++p) s += scores_p[(size_t)p * (B_ * S_) + idx];
        v[k] = s; mx = fmaxf(mx, s);
    }
    for (int mm = 1; mm < 64; mm <<= 1) mx = fmaxf(mx, __shfl_xor(mx, mm));
    if ((t & 63) == 0) red[t >> 6] = mx;
    __syncthreads();
    mx = fmaxf(fmaxf(red[0], red[1]), fmaxf(red[2], red[3]));
    float sum = 0.0f;
#pragma unroll
    for (int k = 0; k < 8; ++k) { v[k] = __expf(v[k] - mx); sum += v[k]; }
    for (int mm = 1; mm < 64; mm <<= 1) sum += __shfl_xor(sum, mm);
    __syncthreads();
    if ((t & 63) == 0) red[t >> 6] = sum;
    __syncthreads();
    sum = red[0] + red[1] + red[2] + red[3];
    float inv = 1.0f / sum;
#pragma unroll
    for (int k = 0; k < 8; ++k) weights[b * S_ + t + k * 256] = v[k] * inv;
}

// ---------------- context stage 1: partial[b*64+sc*2+rp][h] ------------------
__global__ void k_ctx1(const unsigned short* __restrict__ keysbf,
                       const float* __restrict__ weights, float* __restrict__ partial) {
    int blk = blockIdx.x;          // 32 b x 32 s-chunks (64 rows each)
    int b = blk >> 5, sc = blk & 31;
    int t = threadIdx.x;
    __shared__ float wl[64];
    if (t < 64) wl[t] = weights[b * S_ + sc * 64 + t];
    __syncthreads();
    const uint4* kp = (const uint4*)(keysbf + (size_t)(b * S_ + sc * 64) * H_);
    int col = t & 127;             // uint4 col (8 bf16)
    int rp  = t >> 7;              // row parity 0/1
    float a0=0,a1=0,a2=0,a3=0,a4=0,a5=0,a6=0,a7=0;
#pragma unroll 8
    for (int s = rp; s < 64; s += 2) {
        uint4 v = kp[(size_t)s * 128 + col];
        float w = wl[s];
        a0 += w * bf_lo(v.x); a1 += w * bf_hi(v.x);
        a2 += w * bf_lo(v.y); a3 += w * bf_hi(v.y);
        a4 += w * bf_lo(v.z); a5 += w * bf_hi(v.z);
        a6 += w * bf_lo(v.w); a7 += w * bf_hi(v.w);
    }
    float* pp = partial + (size_t)(b * 64 + sc * 2 + rp) * H_ + col * 8;
    float4 o0 = {a0, a1, a2, a3}, o1 = {a4, a5, a6, a7};
    *(float4*)pp = o0;
    *(float4*)(pp + 4) = o1;
}

// ---------------- context stage 2: reduce 64 partials ------------------------
__global__ void k_ctx2(const float* __restrict__ partial, float* __restrict__ ctx) {
    int b = blockIdx.x;
    int t = threadIdx.x;
    float4 a = {0.f, 0.f, 0.f, 0.f};
#pragma unroll 8
    for (int j = 0; j < 64; ++j) {
        float4 p = *(const float4*)(partial + (size_t)(b * 64 + j) * H_ + t * 4);
        a.x += p.x; a.y += p.y; a.z += p.z; a.w += p.w;
    }
    *(float4*)(ctx + b * H_ + t * 4) = a;
}

// -----------------------------------------------------------------------------
extern "C" void kernel_launch(void* const* d_in, const int* in_sizes, int n_in,
                              void* d_out, int out_size, void* d_ws, size_t ws_size,
                              hipStream_t stream) {
    const float* query = (const float*)d_in[0];
    const float* keys  = (const float*)d_in[1];
    const float* Wa_w  = (const float*)d_in[2];
    const float* Wa_b  = (const float*)d_in[3];
    const float* Ua_w  = (const float*)d_in[4];
    const float* Ua_b  = (const float*)d_in[5];
    const float* Va_w  = (const float*)d_in[6];
    // Va_b unused: softmax shift-invariant, scores not an output.

    float* out     = (float*)d_out;
    float* ctx     = out;              // [32,1,1024]
    float* weights = out + B_ * H_;    // [32,2048]

    char* ws = (char*)d_ws;
    unsigned short* keysbf  = (unsigned short*)ws;                          // 128 MB
    unsigned short* uab     = (unsigned short*)(ws + 134217728);            // 2 MB
    float*          qsum    = (float*)(ws + 134217728 + 2097152);           // 128 KB
    float*          scores_p= (float*)(ws + 134217728 + 2097152 + 131072);  // 16 slabs x 256 KB = 4 MB
    float*          partial = (float*)(ws + 134217728 + 2097152 + 131072 + 4194304); // 8 MB

    k_prep   <<<KCVT_BLOCKS + UACVT_BLOCKS + QP_BLOCKS, 256, 0, stream>>>(
        keys, keysbf, Ua_w, uab, query, Wa_w, Wa_b, Ua_b, qsum);
    k_scores <<<1024, 512, 0, stream>>>(keysbf, uab, qsum, Va_w, scores_p);
    k_softmax<<<B_, 256, 0, stream>>>(scores_p, weights);
    k_ctx1   <<<B_ * 32, 256, 0, stream>>>(keysbf, weights, partial);
    k_ctx2   <<<B_, 256, 0, stream>>>(partial, ctx);
}

// Round 3
// 598.773 us; speedup vs baseline: 1.0106x; 1.0106x over previous
//
#include <hip/hip_runtime.h>
#include <hip/hip_bf16.h>
#include <stdint.h>

#define B_ 32
#define S_ 2048
#define H_ 1024

typedef __attribute__((ext_vector_type(8))) short short8;
typedef __attribute__((ext_vector_type(4))) float floatx4;

__device__ inline unsigned short f32_bf16(float f) {
    union { float f; unsigned u; } v; v.f = f;
    unsigned u = v.u;
    u += 0x7fff + ((u >> 16) & 1);   // round-to-nearest-even
    return (unsigned short)(u >> 16);
}
__device__ inline unsigned pack_bf2(float a, float b) {
    return (unsigned)f32_bf16(a) | ((unsigned)f32_bf16(b) << 16);
}
__device__ inline float bf_lo(unsigned u) { union { unsigned u; float f; } v; v.u = u << 16; return v.f; }
__device__ inline float bf_hi(unsigned u) { union { unsigned u; float f; } v; v.u = u & 0xffff0000u; return v.f; }

__device__ inline float tanh_fast(float x) {
    float e = __expf(2.0f * x);
    return 1.0f - 2.0f / (e + 1.0f);
}

__device__ inline void gld16(const void* g, void* l) {
    __builtin_amdgcn_global_load_lds(
        (const __attribute__((address_space(1))) unsigned int*)g,
        (__attribute__((address_space(3))) unsigned int*)l, 16, 0, 0);
}

// ---------------- prep: keys->bf16, Ua->bf16, qproj --------------------------
#define KCVT_BLOCKS 32768          // 64M elems / 2048 per block
#define UACVT_BLOCKS 512           // 1M elems / 2048 per block
#define QP_BLOCKS 64
__global__ void k_prep(const float* __restrict__ keys, unsigned short* __restrict__ keysbf,
                       const float* __restrict__ ua, unsigned short* __restrict__ uab,
                       const float* __restrict__ query, const float* __restrict__ Wa_w,
                       const float* __restrict__ Wa_b, const float* __restrict__ Ua_b,
                       float* __restrict__ qsum) {
    int blk = blockIdx.x, t = threadIdx.x;
    if (blk < KCVT_BLOCKS + UACVT_BLOCKS) {
        const float* src; unsigned short* dst; size_t base;
        if (blk < KCVT_BLOCKS) { src = keys; dst = keysbf; base = (size_t)blk * 2048; }
        else { src = ua; dst = uab; base = (size_t)(blk - KCVT_BLOCKS) * 2048; }
        float4 v0 = *(const float4*)(src + base + t * 4);
        float4 v1 = *(const float4*)(src + base + 1024 + t * 4);
        *(uint2*)(dst + base + t * 4)        = make_uint2(pack_bf2(v0.x, v0.y), pack_bf2(v0.z, v0.w));
        *(uint2*)(dst + base + 1024 + t * 4) = make_uint2(pack_bf2(v1.x, v1.y), pack_bf2(v1.z, v1.w));
    } else {
        // qproj: qsum[b,g] = query[b]·Wa_w[g] + Wa_b[g] + Ua_b[g]
        __shared__ float qs_l[32][68];
        int g0 = (blk - KCVT_BLOCKS - UACVT_BLOCKS) * 16;
        int r = t >> 4, l = t & 15;
        int g = g0 + r;
        float acc[32];
#pragma unroll
        for (int b = 0; b < 32; ++b) acc[b] = 0.0f;
        int sb = t >> 3, sc = (t & 7) * 8;
        for (int hc = 0; hc < 16; ++hc) {
            __syncthreads();
            float4 v0 = *(const float4*)(query + (size_t)sb * H_ + hc * 64 + sc);
            float4 v1 = *(const float4*)(query + (size_t)sb * H_ + hc * 64 + sc + 4);
            *(float4*)&qs_l[sb][sc]     = v0;
            *(float4*)&qs_l[sb][sc + 4] = v1;
            __syncthreads();
            float4 w = *(const float4*)(Wa_w + (size_t)g * H_ + hc * 64 + l * 4);
#pragma unroll
            for (int b = 0; b < 32; ++b) {
                float4 q4 = *(const float4*)&qs_l[b][l * 4];
                acc[b] += w.x * q4.x + w.y * q4.y + w.z * q4.z + w.w * q4.w;
            }
        }
#pragma unroll
        for (int b = 0; b < 32; ++b) {
            float a = acc[b];
            a += __shfl_xor(a, 1); a += __shfl_xor(a, 2);
            a += __shfl_xor(a, 4); a += __shfl_xor(a, 8);
            acc[b] = a;
        }
        if (l == 0) {
            float bias = Wa_b[g] + Ua_b[g];
#pragma unroll
            for (int b = 0; b < 32; ++b) qsum[b * H_ + g] = acc[b] + bias;
        }
    }
}

// ---------------- fused GEMM + tanh + Va reduction ---------------------------
// 256x256 tile, BK=64, 8 waves (2M x 4N). "Loose 4-phase": 2 barriers + 1 vmcnt
// per K-step; waves skew freely inside a step so ds_read/MFMA of different
// waves overlap (intra-block m114 mechanism).
// Half-tiles of tile t: A0,A1 (A rows, interleaved) / B0,B1 (B rows).
// Staging: p1(t) stages {B1,A1}(t+1) -> buf(t^1); p4(t) stages {A0,B0}(t+2)
//   -> buf(t) (safe: A0/B0 regions of buf(t) are only read at p1, and all
//   waves passed the p3-end barrier before any wave reaches p4).
// Single vmcnt(4) at p4-end leaves only {A0,B0}(t+2) outstanding =>
//   guarantees {A0,B0}(t+1) (4-phase lead) + {B1,A1}(t+1) (3-phase lead).
// Phases: p1: read A0,B0 frags, stage, MFMA Q00
//         p2: read B1 frags, MFMA Q01
//         p3: read A1 frags, MFMA Q10, barrier (WAR protect)
//         p4: stage, MFMA Q11, vmcnt(4), barrier (publish)
// Peel: t=14 stages only {B1,A1}(15), vmcnt(0); t=15 bare.
#define BM 256
#define BN 256
#define BK 64

#define VMCNT(S) asm volatile("s_waitcnt vmcnt(" S ")" ::: "memory")

#define STAGE_A(SB, h, KO) do {                                                       \
    gld16(pAj[0] + (h) * 64 * H_ + (KO), &Al[(SB) * 16384 + (h) * 8192 + sA]);        \
    gld16(pAj[1] + (h) * 64 * H_ + (KO), &Al[(SB) * 16384 + (h) * 8192 + sA + 512]);  \
} while (0)
#define STAGE_B(SB, h, KO) do {                                                       \
    gld16(pBj[0] + (h) * 32 * H_ + (KO), &Bl[(SB) * 16384 + (h) * 8192 + sA]);        \
    gld16(pBj[1] + (h) * 32 * H_ + (KO), &Bl[(SB) * 16384 + (h) * 8192 + sA + 512]);  \
} while (0)

#define MFMA_BF16 __builtin_amdgcn_mfma_f32_16x16x32_bf16

// STEP(RB, SB1, SB2, KO1, KO2, DOST1, DOST2, DOBAR, WS)
// RB: read-buffer elem offset (0/16384). SB1: stage buf for {B1,A1}(t+1).
// SB2: stage buf for {A0,B0}(t+2). KO1/KO2: their k elem offsets.
#define STEP(RB, SB1, SB2, KO1, KO2, DOST1, DOST2, DOBAR, WS) do {                     \
    /* phase 1: read A0,B0(cur); stage {B1,A1}(t+1); MFMA Q00 */                       \
    _Pragma("unroll") for (int ii_ = 0; ii_ < 4; ++ii_) {                              \
        af[ii_][0] = *(const short8*)&Al[(RB) + arA + ii_ * 1024 + cs0];               \
        af[ii_][1] = *(const short8*)&Al[(RB) + arA + ii_ * 1024 + cs1]; }             \
    _Pragma("unroll") for (int jj_ = 0; jj_ < 2; ++jj_) {                              \
        bfa[jj_][0] = *(const short8*)&Bl[(RB) + brB + jj_ * 1024 + cs0];              \
        bfa[jj_][1] = *(const short8*)&Bl[(RB) + brB + jj_ * 1024 + cs1]; }            \
    if (DOST1) { STAGE_B(SB1, 1, KO1); STAGE_A(SB1, 1, KO1); }                         \
    __builtin_amdgcn_s_setprio(1);                                                     \
    _Pragma("unroll") for (int ii_ = 0; ii_ < 4; ++ii_)                                \
    _Pragma("unroll") for (int jj_ = 0; jj_ < 2; ++jj_) {                              \
        acc[ii_][jj_] = MFMA_BF16(af[ii_][0], bfa[jj_][0], acc[ii_][jj_], 0, 0, 0);    \
        acc[ii_][jj_] = MFMA_BF16(af[ii_][1], bfa[jj_][1], acc[ii_][jj_], 0, 0, 0); }  \
    __builtin_amdgcn_s_setprio(0);                                                     \
    /* phase 2: read B1(cur); MFMA Q01 */                                              \
    _Pragma("unroll") for (int jj_ = 0; jj_ < 2; ++jj_) {                              \
        bfb[jj_][0] = *(const short8*)&Bl[(RB) + 8192 + brB + jj_ * 1024 + cs0];       \
        bfb[jj_][1] = *(const short8*)&Bl[(RB) + 8192 + brB + jj_ * 1024 + cs1]; }     \
    __builtin_amdgcn_s_setprio(1);                                                     \
    _Pragma("unroll") for (int ii_ = 0; ii_ < 4; ++ii_)                                \
    _Pragma("unroll") for (int jj_ = 0; jj_ < 2; ++jj_) {                              \
        acc[ii_][jj_ + 2] = MFMA_BF16(af[ii_][0], bfb[jj_][0], acc[ii_][jj_ + 2], 0, 0, 0); \
        acc[ii_][jj_ + 2] = MFMA_BF16(af[ii_][1], bfb[jj_][1], acc[ii_][jj_ + 2], 0, 0, 0); } \
    __builtin_amdgcn_s_setprio(0);                                                     \
    /* phase 3: read A1(cur); MFMA Q10; barrier (WAR) */                               \
    _Pragma("unroll") for (int ii_ = 0; ii_ < 4; ++ii_) {                              \
        af[ii_][0] = *(const short8*)&Al[(RB) + 8192 + arA + ii_ * 1024 + cs0];        \
        af[ii_][1] = *(const short8*)&Al[(RB) + 8192 + arA + ii_ * 1024 + cs1]; }      \
    __builtin_amdgcn_s_setprio(1);                                                     \
    _Pragma("unroll") for (int ii_ = 0; ii_ < 4; ++ii_)                                \
    _Pragma("unroll") for (int jj_ = 0; jj_ < 2; ++jj_) {                              \
        acc[ii_ + 4][jj_] = MFMA_BF16(af[ii_][0], bfa[jj_][0], acc[ii_ + 4][jj_], 0, 0, 0); \
        acc[ii_ + 4][jj_] = MFMA_BF16(af[ii_][1], bfa[jj_][1], acc[ii_ + 4][jj_], 0, 0, 0); } \
    __builtin_amdgcn_s_setprio(0);                                                     \
    if (DOBAR) __builtin_amdgcn_s_barrier();                                           \
    /* phase 4: stage {A0,B0}(t+2); MFMA Q11; vmcnt; barrier (publish) */              \
    if (DOST2) { STAGE_A(SB2, 0, KO2); STAGE_B(SB2, 0, KO2); }                         \
    __builtin_amdgcn_s_setprio(1);                                                     \
    _Pragma("unroll") for (int ii_ = 0; ii_ < 4; ++ii_)                                \
    _Pragma("unroll") for (int jj_ = 0; jj_ < 2; ++jj_) {                              \
        acc[ii_ + 4][jj_ + 2] = MFMA_BF16(af[ii_][0], bfb[jj_][0], acc[ii_ + 4][jj_ + 2], 0, 0, 0); \
        acc[ii_ + 4][jj_ + 2] = MFMA_BF16(af[ii_][1], bfb[jj_][1], acc[ii_ + 4][jj_ + 2], 0, 0, 0); } \
    __builtin_amdgcn_s_setprio(0);                                                     \
    if (DOBAR) { VMCNT(WS); __builtin_amdgcn_s_barrier(); }                            \
} while (0)

__global__ __launch_bounds__(512, 2) void k_scores(
    const unsigned short* __restrict__ keysbf, const unsigned short* __restrict__ uab,
    const float* __restrict__ qsum, const float* __restrict__ va,
    float* __restrict__ scores_p)
{
    __shared__ unsigned short Al[32768];   // 64 KB: [buf2][half2][128][64] swizzled
    __shared__ unsigned short Bl[32768];   // 64 KB

    int bx = blockIdx.x;                   // 1024 blocks: 256 m-tiles x 4 nc
    int x  = bx & 7;                       // XCD
    int i  = bx >> 3;
    int tile_m = x * 32 + (i >> 2);
    int nc     = i & 3;
    int m_base = tile_m * BM;
    int b      = m_base >> 11;
    int g0     = nc * BN;

    int tid = threadIdx.x;
    int wid = tid >> 6, lane = tid & 63;
    int wm = wid >> 2, wn = wid & 3;       // 2 x 4 wave grid; wave tile 128 x 64
    int q = lane >> 4, cn = lane & 15;
    int c7 = cn & 7;

    // ---- staging geometry: chunk (wid*2+j) covers half-local rows chunk*8..+8.
    // phys col-group (lane&7) holds global col-group (lane&7)^(hlrow&7).
    int rl8 = lane >> 3;
    int gcg = (lane & 7) ^ rl8;
    int ch0 = wid * 2;
    const unsigned short* pAj[2];
    const unsigned short* pBj[2];
#pragma unroll
    for (int j = 0; j < 2; ++j) {
        int hlrow = (ch0 + j) * 8 + rl8;
        // A half-local row -> global row (half0; half1 adds 64*H_ at use)
        pAj[j] = keysbf + (size_t)(m_base + (hlrow >> 6) * 128 + (hlrow & 63)) * H_ + gcg * 8;
        // B half-local row -> global g-row (half0; half1 adds 32*H_ at use)
        pBj[j] = uab    + (size_t)(g0 + (hlrow >> 5) * 64 + (hlrow & 31)) * H_ + gcg * 8;
    }
    int sA = ch0 * 512;                    // LDS elem offset of this wave's chunk 0

    // ---- fragment read bases (within one half of one buffer)
    int arA = wm * 4096 + cn * 64;         // A: hr = wm*64 + (ii&3)*16 + cn
    int brB = wn * 2048 + cn * 64;         // B: hr = wn*32 + (jj&1)*16 + cn
    int cs0 = (q ^ c7) * 8;                // phys col-group, kk=0
    int cs1 = ((4 + q) ^ c7) * 8;          // phys col-group, kk=1

    floatx4 acc[8][4];
#pragma unroll
    for (int ii = 0; ii < 8; ++ii)
#pragma unroll
        for (int jj = 0; jj < 4; ++jj)
            acc[ii][jj] = (floatx4)(0.0f);

    short8 af[4][2], bfa[2][2], bfb[2][2];

    // ---- prologue: stage tile 0 (both buf0 halves) + {A0,B0}(1) into buf1;
    // vmcnt(4) leaves only {A0,B0}(1) outstanding -> all of tile 0 published.
    STAGE_A(0, 0, 0);  STAGE_B(0, 0, 0);    // {A0,B0}(0)
    STAGE_B(0, 1, 0);  STAGE_A(0, 1, 0);    // {B1,A1}(0)
    STAGE_A(1, 0, 64); STAGE_B(1, 0, 64);   // {A0,B0}(1)
    VMCNT("4");
    __builtin_amdgcn_s_barrier();

    // ---- main loop: 16 K-steps
#pragma unroll 1
    for (int it = 0; it < 7; ++it) {
        int t2 = it * 2;
        STEP(0,     1, 0, (t2 + 1) * 64, (t2 + 2) * 64, 1, 1, 1, "4");
        STEP(16384, 0, 1, (t2 + 2) * 64, (t2 + 3) * 64, 1, 1, 1, "4");
    }
    STEP(0,     1, 0, 960, 0, 1, 0, 1, "0");   // t=14: stage {B1,A1}(15); drain
    STEP(16384, 0, 1, 0,   0, 0, 0, 0, "0");   // t=15: bare

    // ---- epilogue: scores partial = sum_g Va[g] * tanh(qsum[b,g] + C)
    float qs[4], vw[4];
#pragma unroll
    for (int jj = 0; jj < 4; ++jj) {
        int g = g0 + wn * 64 + jj * 16 + cn;
        qs[jj] = qsum[b * H_ + g];
        vw[jj] = va[g];
    }
    float* slab = scores_p + (size_t)(wn * 4 + nc) * (B_ * S_) + b * S_;
#pragma unroll
    for (int ii = 0; ii < 8; ++ii) {
        float rs[4] = {0.f, 0.f, 0.f, 0.f};
#pragma unroll
        for (int jj = 0; jj < 4; ++jj) {
#pragma unroll
            for (int r = 0; r < 4; ++r)
                rs[r] += vw[jj] * tanh_fast(qs[jj] + acc[ii][jj][r]);
        }
#pragma unroll
        for (int r = 0; r < 4; ++r) {
            rs[r] += __shfl_xor(rs[r], 1); rs[r] += __shfl_xor(rs[r], 2);
            rs[r] += __shfl_xor(rs[r], 4); rs[r] += __shfl_xor(rs[r], 8);
        }
        if (cn == 0) {
            int msrow = (m_base & (S_ - 1)) + wm * 128 + ii * 16 + q * 4;
            float* sp = slab + msrow;
            sp[0] = rs[0]; sp[1] = rs[1]; sp[2] = rs[2]; sp[3] = rs[3];
        }
    }
}

// ---------------- softmax over S per batch (reduces 16 partial slabs) --------
__global__ void k_softmax(const float* __restrict__ scores_p, float* __restrict__ weights) {
    int b = blockIdx.x;
    int t = threadIdx.x;
    __shared__ float red[4];
    float v[8];
    float mx = -1e30f;
#pragma unroll
    for (int k = 0; k < 8; ++k) {
        int idx = b * S_ + t + k * 256;
        float s = 0.0f;
#pragma unroll
        for (int p = 0; p < 16; ++p) s += scores_p[(size_t)p * (B_ * S_) + idx];
        v[k] = s; mx = fmaxf(mx, s);
    }
    for (int mm = 1; mm < 64; mm <<= 1) mx = fmaxf(mx, __shfl_xor(mx, mm));
    if ((t & 63) == 0) red[t >> 6] = mx;
    __syncthreads();
    mx = fmaxf(fmaxf(red[0], red[1]), fmaxf(red[2], red[3]));
    float sum = 0.0f;
#pragma unroll
    for (int k = 0; k < 8; ++k) { v[k] = __expf(v[k] - mx); sum += v[k]; }
    for (int mm = 1; mm < 64; mm <<= 1) sum += __shfl_xor(sum, mm);
    __syncthreads();
    if ((t & 63) == 0) red[t >> 6] = sum;
    __syncthreads();
    sum = red[0] + red[1] + red[2] + red[3];
    float inv = 1.0f / sum;
#pragma unroll
    for (int k = 0; k < 8; ++k) weights[b * S_ + t + k * 256] = v[k] * inv;
}

// ---------------- context stage 1: partial[b*64+sc*2+rp][h] ------------------
__global__ void k_ctx1(const unsigned short* __restrict__ keysbf,
                       const float* __restrict__ weights, float* __restrict__ partial) {
    int blk = blockIdx.x;          // 32 b x 32 s-chunks (64 rows each)
    int b = blk >> 5, sc = blk & 31;
    int t = threadIdx.x;
    __shared__ float wl[64];
    if (t < 64) wl[t] = weights[b * S_ + sc * 64 + t];
    __syncthreads();
    const uint4* kp = (const uint4*)(keysbf + (size_t)(b * S_ + sc * 64) * H_);
    int col = t & 127;             // uint4 col (8 bf16)
    int rp  = t >> 7;              // row parity 0/1
    float a0=0,a1=0,a2=0,a3=0,a4=0,a5=0,a6=0,a7=0;
#pragma unroll 8
    for (int s = rp; s < 64; s += 2) {
        uint4 v = kp[(size_t)s * 128 + col];
        float w = wl[s];
        a0 += w * bf_lo(v.x); a1 += w * bf_hi(v.x);
        a2 += w * bf_lo(v.y); a3 += w * bf_hi(v.y);
        a4 += w * bf_lo(v.z); a5 += w * bf_hi(v.z);
        a6 += w * bf_lo(v.w); a7 += w * bf_hi(v.w);
    }
    float* pp = partial + (size_t)(b * 64 + sc * 2 + rp) * H_ + col * 8;
    float4 o0 = {a0, a1, a2, a3}, o1 = {a4, a5, a6, a7};
    *(float4*)pp = o0;
    *(float4*)(pp + 4) = o1;
}

// ---------------- context stage 2: reduce 64 partials ------------------------
__global__ void k_ctx2(const float* __restrict__ partial, float* __restrict__ ctx) {
    int b = blockIdx.x;
    int t = threadIdx.x;
    float4 a = {0.f, 0.f, 0.f, 0.f};
#pragma unroll 8
    for (int j = 0; j < 64; ++j) {
        float4 p = *(const float4*)(partial + (size_t)(b * 64 + j) * H_ + t * 4);
        a.x += p.x; a.y += p.y; a.z += p.z; a.w += p.w;
    }
    *(float4*)(ctx + b * H_ + t * 4) = a;
}

// -----------------------------------------------------------------------------
extern "C" void kernel_launch(void* const* d_in, const int* in_sizes, int n_in,
                              void* d_out, int out_size, void* d_ws, size_t ws_size,
                              hipStream_t stream) {
    const float* query = (const float*)d_in[0];
    const float* keys  = (const float*)d_in[1];
    const float* Wa_w  = (const float*)d_in[2];
    const float* Wa_b  = (const float*)d_in[3];
    const float* Ua_w  = (const float*)d_in[4];
    const float* Ua_b  = (const float*)d_in[5];
    const float* Va_w  = (const float*)d_in[6];
    // Va_b unused: softmax shift-invariant, scores not an output.

    float* out     = (float*)d_out;
    float* ctx     = out;              // [32,1,1024]
    float* weights = out + B_ * H_;    // [32,2048]

    char* ws = (char*)d_ws;
    unsigned short* keysbf  = (unsigned short*)ws;                          // 128 MB
    unsigned short* uab     = (unsigned short*)(ws + 134217728);            // 2 MB
    float*          qsum    = (float*)(ws + 134217728 + 2097152);           // 128 KB
    float*          scores_p= (float*)(ws + 134217728 + 2097152 + 131072);  // 16 slabs x 256 KB = 4 MB
    float*          partial = (float*)(ws + 134217728 + 2097152 + 131072 + 4194304); // 8 MB

    k_prep   <<<KCVT_BLOCKS + UACVT_BLOCKS + QP_BLOCKS, 256, 0, stream>>>(
        keys, keysbf, Ua_w, uab, query, Wa_w, Wa_b, Ua_b, qsum);
    k_scores <<<1024, 512, 0, stream>>>(keysbf, uab, qsum, Va_w, scores_p);
    k_softmax<<<B_, 256, 0, stream>>>(scores_p, weights);
    k_ctx1   <<<B_ * 32, 256, 0, stream>>>(keysbf, weights, partial);
    k_ctx2   <<<B_, 256, 0, stream>>>(partial, ctx);
}

// Round 4
// 584.058 us; speedup vs baseline: 1.0361x; 1.0252x over previous
//
#include <hip/hip_runtime.h>
#include <hip/hip_bf16.h>
#include <stdint.h>

#define B_ 32
#define S_ 2048
#define H_ 1024

typedef __attribute__((ext_vector_type(8))) short short8;
typedef __attribute__((ext_vector_type(4))) float floatx4;

__device__ inline unsigned short f32_bf16(float f) {
    union { float f; unsigned u; } v; v.f = f;
    unsigned u = v.u;
    u += 0x7fff + ((u >> 16) & 1);   // round-to-nearest-even
    return (unsigned short)(u >> 16);
}
__device__ inline unsigned pack_bf2(float a, float b) {
    return (unsigned)f32_bf16(a) | ((unsigned)f32_bf16(b) << 16);
}
__device__ inline float bf_lo(unsigned u) { union { unsigned u; float f; } v; v.u = u << 16; return v.f; }
__device__ inline float bf_hi(unsigned u) { union { unsigned u; float f; } v; v.u = u & 0xffff0000u; return v.f; }

__device__ inline float tanh_fast(float x) {
    float e = __expf(2.0f * x);
    return 1.0f - 2.0f / (e + 1.0f);
}

__device__ inline void gld16(const void* g, void* l) {
    __builtin_amdgcn_global_load_lds(
        (const __attribute__((address_space(1))) unsigned int*)g,
        (__attribute__((address_space(3))) unsigned int*)l, 16, 0, 0);
}

// ---------------- prep: keys->bf16, Ua->bf16, qproj --------------------------
#define KCVT_BLOCKS 32768          // 64M elems / 2048 per block
#define UACVT_BLOCKS 512           // 1M elems / 2048 per block
#define QP_BLOCKS 64
__global__ void k_prep(const float* __restrict__ keys, unsigned short* __restrict__ keysbf,
                       const float* __restrict__ ua, unsigned short* __restrict__ uab,
                       const float* __restrict__ query, const float* __restrict__ Wa_w,
                       const float* __restrict__ Wa_b, const float* __restrict__ Ua_b,
                       float* __restrict__ qsum) {
    int blk = blockIdx.x, t = threadIdx.x;
    if (blk < KCVT_BLOCKS + UACVT_BLOCKS) {
        const float* src; unsigned short* dst; size_t base;
        if (blk < KCVT_BLOCKS) { src = keys; dst = keysbf; base = (size_t)blk * 2048; }
        else { src = ua; dst = uab; base = (size_t)(blk - KCVT_BLOCKS) * 2048; }
        float4 v0 = *(const float4*)(src + base + t * 4);
        float4 v1 = *(const float4*)(src + base + 1024 + t * 4);
        *(uint2*)(dst + base + t * 4)        = make_uint2(pack_bf2(v0.x, v0.y), pack_bf2(v0.z, v0.w));
        *(uint2*)(dst + base + 1024 + t * 4) = make_uint2(pack_bf2(v1.x, v1.y), pack_bf2(v1.z, v1.w));
    } else {
        // qproj: qsum[b,g] = query[b]·Wa_w[g] + Wa_b[g] + Ua_b[g]
        __shared__ float qs_l[32][68];
        int g0 = (blk - KCVT_BLOCKS - UACVT_BLOCKS) * 16;
        int r = t >> 4, l = t & 15;
        int g = g0 + r;
        float acc[32];
#pragma unroll
        for (int b = 0; b < 32; ++b) acc[b] = 0.0f;
        int sb = t >> 3, sc = (t & 7) * 8;
        for (int hc = 0; hc < 16; ++hc) {
            __syncthreads();
            float4 v0 = *(const float4*)(query + (size_t)sb * H_ + hc * 64 + sc);
            float4 v1 = *(const float4*)(query + (size_t)sb * H_ + hc * 64 + sc + 4);
            *(float4*)&qs_l[sb][sc]     = v0;
            *(float4*)&qs_l[sb][sc + 4] = v1;
            __syncthreads();
            float4 w = *(const float4*)(Wa_w + (size_t)g * H_ + hc * 64 + l * 4);
#pragma unroll
            for (int b = 0; b < 32; ++b) {
                float4 q4 = *(const float4*)&qs_l[b][l * 4];
                acc[b] += w.x * q4.x + w.y * q4.y + w.z * q4.z + w.w * q4.w;
            }
        }
#pragma unroll
        for (int b = 0; b < 32; ++b) {
            float a = acc[b];
            a += __shfl_xor(a, 1); a += __shfl_xor(a, 2);
            a += __shfl_xor(a, 4); a += __shfl_xor(a, 8);
            acc[b] = a;
        }
        if (l == 0) {
            float bias = Wa_b[g] + Ua_b[g];
#pragma unroll
            for (int b = 0; b < 32; ++b) qsum[b * H_ + g] = acc[b] + bias;
        }
    }
}

// ---------------- fused GEMM + tanh + Va reduction ---------------------------
// (round-0 structure: 128x128 tile, BK=64, 4 waves, 4 blocks/CU — known 172 µs)
// C[ms,g] = sum_h keysbf[ms,h] * uab[g,h]  (NT, bf16 MFMA 16x16x32), BK=64
// scores_p[nc][ms] = sum_{g in chunk nc} Va[g] * tanh(qsum[b,g] + C[ms,g])
#define BM 128
#define BN 128
#define BK 64

__global__ __launch_bounds__(256, 4) void k_scores(
    const unsigned short* __restrict__ keysbf, const unsigned short* __restrict__ uab,
    const float* __restrict__ qsum, const float* __restrict__ va,
    float* __restrict__ scores_p)
{
    __shared__ unsigned short Al[BM * BK];   // 16 KB, row-major [128][64], col-group swizzled
    __shared__ unsigned short Bl[BN * BK];   // 16 KB

    int bx = blockIdx.x;
    int x  = bx & 7;                   // XCD
    int i  = bx >> 3;
    int tile_m = x * 64 + (i >> 3);
    int nc     = i & 7;
    int m_base = tile_m * BM;
    int b      = m_base >> 11;
    int g0     = nc * BN;

    int tid = threadIdx.x;
    int wid = tid >> 6, lane = tid & 63;
    int wm = wid >> 1, wn = wid & 1;
    int q = lane >> 4, cn = lane & 15;

    // ---- staging (global_load_lds, 16B/lane): call j stages 8 rows x 8 col-groups.
    // phys col-group (lane&7) holds global col-group (lane&7)^(row&7); row&7 == lane>>3.
    int rl8 = lane >> 3;               // row within call, also row&7
    int gcg = (lane & 7) ^ rl8;        // fetched global col-group
    const unsigned short* pA[4];
    const unsigned short* pB[4];
    unsigned short* lA[4];
    unsigned short* lB[4];
#pragma unroll
    for (int j = 0; j < 4; ++j) {
        int row = wid * 32 + j * 8 + rl8;
        pA[j] = keysbf + (size_t)(m_base + row) * H_ + gcg * 8;
        pB[j] = uab    + (size_t)(g0     + row) * H_ + gcg * 8;
        lA[j] = &Al[(wid * 32 + j * 8) * BK];
        lB[j] = &Bl[(wid * 32 + j * 8) * BK];
    }

    // ---- fragment read offsets: row r, k-chunk kk (0/1), col = kk*32+q*8
    int aoff[2][4], boff[2][4];
#pragma unroll
    for (int kk = 0; kk < 2; ++kk)
#pragma unroll
        for (int ii = 0; ii < 4; ++ii) {
            int r  = wm * 64 + ii * 16 + cn;
            aoff[kk][ii] = r * BK + ((kk * 4 + q) ^ (r & 7)) * 8;
            int rb = wn * 64 + ii * 16 + cn;
            boff[kk][ii] = rb * BK + ((kk * 4 + q) ^ (rb & 7)) * 8;
        }

    floatx4 acc[4][4];
#pragma unroll
    for (int ii = 0; ii < 4; ++ii)
#pragma unroll
        for (int jj = 0; jj < 4; ++jj)
            acc[ii][jj] = (floatx4)(0.0f);

    for (int kc = 0; kc < H_ / BK; ++kc) {
        __syncthreads();
        int ko = kc * BK;
#pragma unroll
        for (int j = 0; j < 4; ++j) {
            gld16(pA[j] + ko, lA[j]);
            gld16(pB[j] + ko, lB[j]);
        }
        __syncthreads();
#pragma unroll
        for (int kk = 0; kk < 2; ++kk) {
            short8 af[4], bf[4];
#pragma unroll
            for (int ii = 0; ii < 4; ++ii) af[ii] = *(const short8*)&Al[aoff[kk][ii]];
#pragma unroll
            for (int jj = 0; jj < 4; ++jj) bf[jj] = *(const short8*)&Bl[boff[kk][jj]];
#pragma unroll
            for (int ii = 0; ii < 4; ++ii)
#pragma unroll
                for (int jj = 0; jj < 4; ++jj)
                    acc[ii][jj] = __builtin_amdgcn_mfma_f32_16x16x32_bf16(
                        af[ii], bf[jj], acc[ii][jj], 0, 0, 0);
        }
    }

    // epilogue: scores_p partial = sum_g Va[g] * tanh(qsum[b,g] + C)
    float qs[4], vw[4];
#pragma unroll
    for (int jj = 0; jj < 4; ++jj) {
        int g = g0 + wn * 64 + jj * 16 + cn;
        qs[jj] = qsum[b * H_ + g];
        vw[jj] = va[g];
    }
    float* slab = scores_p + (size_t)nc * (B_ * S_) + b * S_;
#pragma unroll
    for (int ii = 0; ii < 4; ++ii) {
        float rs[4] = {0.f, 0.f, 0.f, 0.f};
#pragma unroll
        for (int jj = 0; jj < 4; ++jj) {
#pragma unroll
            for (int r = 0; r < 4; ++r)
                rs[r] += vw[jj] * tanh_fast(qs[jj] + acc[ii][jj][r]);
        }
#pragma unroll
        for (int r = 0; r < 4; ++r) {
            for (int mm = 1; mm < 16; mm <<= 1)
                rs[r] += __shfl_xor(rs[r], mm);
        }
        if (cn == 0) {
            int msrow = (m_base & (S_ - 1)) + wm * 64 + ii * 16 + q * 4;
            float* sp = slab + (size_t)wn * (8 * B_ * S_) + msrow;
            sp[0] = rs[0]; sp[1] = rs[1]; sp[2] = rs[2]; sp[3] = rs[3];
        }
    }
}

// ---------------- softmax over S per batch (reduces 16 partial slabs) --------
// 1024 threads, 2 elements/thread (was 256 thr x 8 — 4x more parallelism in the
// latency-bound 16-slab gather).
__global__ void k_softmax(const float* __restrict__ scores_p, float* __restrict__ weights) {
    int b = blockIdx.x;
    int t = threadIdx.x;
    __shared__ float redm[16];
    __shared__ float reds[16];
    int wv = t >> 6;
    float v0 = 0.0f, v1 = 0.0f;
#pragma unroll
    for (int p = 0; p < 16; ++p) {
        const float* sp = scores_p + (size_t)p * (B_ * S_) + b * S_;
        v0 += sp[t];
        v1 += sp[t + 1024];
    }
    float mx = fmaxf(v0, v1);
    for (int mm = 1; mm < 64; mm <<= 1) mx = fmaxf(mx, __shfl_xor(mx, mm));
    if ((t & 63) == 0) redm[wv] = mx;
    __syncthreads();
#pragma unroll
    for (int i = 0; i < 16; ++i) mx = fmaxf(mx, redm[i]);
    float e0 = __expf(v0 - mx), e1 = __expf(v1 - mx);
    float sum = e0 + e1;
    for (int mm = 1; mm < 64; mm <<= 1) sum += __shfl_xor(sum, mm);
    if ((t & 63) == 0) reds[wv] = sum;
    __syncthreads();
    sum = 0.0f;
#pragma unroll
    for (int i = 0; i < 16; ++i) sum += reds[i];
    float inv = 1.0f / sum;
    weights[b * S_ + t]        = e0 * inv;
    weights[b * S_ + t + 1024] = e1 * inv;
}

// ---------------- context: fused (replaces ctx1 + ctx2) ----------------------
// 256 blocks = 32 b x 8 col-chunks (128 floats each), 512 threads.
// Thread (rg = t>>4 in [0,32), c = t&15): accumulates rows s = rg, rg+32, ...
// over its 8-bf16 column group; LDS tree-reduce over the 32 row-groups.
__global__ void k_ctx(const unsigned short* __restrict__ keysbf,
                      const float* __restrict__ weights, float* __restrict__ ctx) {
    int blk = blockIdx.x;
    int b = blk >> 3, cc = blk & 7;
    int t = threadIdx.x;
    __shared__ float wl[2048];          // 8 KB
    __shared__ float red[32][16][9];    // 18 KB (pad 9 -> conflict-light)
#pragma unroll
    for (int k = 0; k < 4; ++k) wl[t + k * 512] = weights[b * S_ + t + k * 512];
    __syncthreads();
    int c = t & 15, rg = t >> 4;
    const uint4* kp = (const uint4*)(keysbf + (size_t)b * S_ * H_) + (size_t)cc * 16 + c;
    float a[8] = {0.f, 0.f, 0.f, 0.f, 0.f, 0.f, 0.f, 0.f};
#pragma unroll 4
    for (int s = rg; s < S_; s += 32) {
        uint4 v = kp[(size_t)s * 128];
        float w = wl[s];
        a[0] += w * bf_lo(v.x); a[1] += w * bf_hi(v.x);
        a[2] += w * bf_lo(v.y); a[3] += w * bf_hi(v.y);
        a[4] += w * bf_lo(v.z); a[5] += w * bf_hi(v.z);
        a[6] += w * bf_lo(v.w); a[7] += w * bf_hi(v.w);
    }
#pragma unroll
    for (int j = 0; j < 8; ++j) red[rg][c][j] = a[j];
    __syncthreads();
    if (t < 128) {
        int c2 = t & 15, j = t >> 4;
        float s = 0.0f;
#pragma unroll
        for (int g = 0; g < 32; ++g) s += red[g][c2][j];
        ctx[b * H_ + cc * 128 + c2 * 8 + j] = s;
    }
}

// -----------------------------------------------------------------------------
extern "C" void kernel_launch(void* const* d_in, const int* in_sizes, int n_in,
                              void* d_out, int out_size, void* d_ws, size_t ws_size,
                              hipStream_t stream) {
    const float* query = (const float*)d_in[0];
    const float* keys  = (const float*)d_in[1];
    const float* Wa_w  = (const float*)d_in[2];
    const float* Wa_b  = (const float*)d_in[3];
    const float* Ua_w  = (const float*)d_in[4];
    const float* Ua_b  = (const float*)d_in[5];
    const float* Va_w  = (const float*)d_in[6];
    // Va_b unused: softmax shift-invariant, scores not an output.

    float* out     = (float*)d_out;
    float* ctx     = out;              // [32,1,1024]
    float* weights = out + B_ * H_;    // [32,2048]

    char* ws = (char*)d_ws;
    unsigned short* keysbf  = (unsigned short*)ws;                          // 128 MB
    unsigned short* uab     = (unsigned short*)(ws + 134217728);            // 2 MB
    float*          qsum    = (float*)(ws + 134217728 + 2097152);           // 128 KB
    float*          scores_p= (float*)(ws + 134217728 + 2097152 + 131072);  // 16 slabs x 256 KB = 4 MB

    k_prep   <<<KCVT_BLOCKS + UACVT_BLOCKS + QP_BLOCKS, 256, 0, stream>>>(
        keys, keysbf, Ua_w, uab, query, Wa_w, Wa_b, Ua_b, qsum);
    k_scores <<<4096, 256, 0, stream>>>(keysbf, uab, qsum, Va_w, scores_p);
    k_softmax<<<B_, 1024, 0, stream>>>(scores_p, weights);
    k_ctx    <<<B_ * 8, 512, 0, stream>>>(keysbf, weights, ctx);
}